// Round 13
// baseline (651.598 us; speedup 1.0000x reference)
//
#include <hip/hip_runtime.h>

typedef unsigned short u16;
typedef __attribute__((ext_vector_type(8))) short short8;
typedef __attribute__((ext_vector_type(4))) float f32x4;

#define NROWS   4096     // B*S
#define S_LEN   2048
#define NHEADS  24
#define DMODEL  3072
#define QPROJ   1536
#define KVPROJ  2048
#define CKV_W   2112     // KVPROJ + 64 rope
#define UKV_N   4608     // DMODEL + 24*64

__device__ __forceinline__ float bf2f(u16 v) {
    unsigned u = ((unsigned)v) << 16; float f; __builtin_memcpy(&f, &u, 4); return f;
}
__device__ __forceinline__ u16 f2bf(float f) {
    unsigned u; __builtin_memcpy(&u, &f, 4);
    u = (u + 0x7FFFu + ((u >> 16) & 1u)) >> 16; return (u16)u;
}
__device__ __forceinline__ void async16(const u16* g, u16* l) {
    __builtin_amdgcn_global_load_lds((const __attribute__((address_space(1))) unsigned int*)g,
                                     (__attribute__((address_space(3))) unsigned int*)l,
                                     16, 0, 0);
}

// ---------------- elementwise convert fp32 -> bf16 (vectorized) -------------
__global__ void conv_bf16(const float* __restrict__ X, u16* __restrict__ Y, int n) {
    int i = (blockIdx.x * 256 + threadIdx.x) * 4;
    if (i >= n) return;
    float4 v = *(const float4*)(X + i);
    Y[i+0] = f2bf(v.x); Y[i+1] = f2bf(v.y); Y[i+2] = f2bf(v.z); Y[i+3] = f2bf(v.w);
}

// ---------------- transpose + convert + scale: W (K x N) -> WT (N x K) bf16 -
__global__ void transpose_bf16(const float* __restrict__ W, u16* __restrict__ WT,
                               int K, int N, float scale) {
    __shared__ float t[32][33];
    int nb = blockIdx.x * 32, kb = blockIdx.y * 32;
    int c = threadIdx.x & 31, rq = threadIdx.x >> 5;
#pragma unroll
    for (int i = 0; i < 4; ++i) {
        int r = rq * 4 + i;
        t[r][c] = W[(size_t)(kb + r) * N + nb + c];
    }
    __syncthreads();
#pragma unroll
    for (int i = 0; i < 4; ++i) {
        int r = rq * 4 + i;
        WT[(size_t)(nb + r) * K + kb + c] = f2bf(t[c][r] * scale);
    }
}

// ---------------- LayerNorm (fp32 in, bf16 out), float4-vectorized ----------
__global__ __launch_bounds__(256) void ln_kernel(const float* __restrict__ X, int ldx,
                                                 const float* __restrict__ g,
                                                 const float* __restrict__ b,
                                                 u16* __restrict__ Y, int W) {
    int row = blockIdx.x;
    const float4* x4 = (const float4*)(X + (size_t)row * ldx);
    int W4 = W >> 2;
    float s = 0.f, s2 = 0.f;
    for (int i = threadIdx.x; i < W4; i += 256) {
        float4 v = x4[i];
        s += v.x + v.y + v.z + v.w;
        s2 += v.x * v.x + v.y * v.y + v.z * v.z + v.w * v.w;
    }
#pragma unroll
    for (int off = 32; off >= 1; off >>= 1) { s += __shfl_xor(s, off); s2 += __shfl_xor(s2, off); }
    __shared__ float red[8];
    int w = threadIdx.x >> 6;
    if ((threadIdx.x & 63) == 0) { red[w] = s; red[4 + w] = s2; }
    __syncthreads();
    s  = red[0] + red[1] + red[2] + red[3];
    s2 = red[4] + red[5] + red[6] + red[7];
    float mean = s / W;
    float var  = s2 / W - mean * mean;
    float rstd = rsqrtf(var + 1e-5f);
    const float4* g4 = (const float4*)g;
    const float4* b4 = (const float4*)b;
    u16* y = Y + (size_t)row * W;
    for (int i = threadIdx.x; i < W4; i += 256) {
        float4 v = x4[i], gg = g4[i], bb = b4[i];
        u16 o[4];
        o[0] = f2bf((v.x - mean) * rstd * gg.x + bb.x);
        o[1] = f2bf((v.y - mean) * rstd * gg.y + bb.y);
        o[2] = f2bf((v.z - mean) * rstd * gg.z + bb.z);
        o[3] = f2bf((v.w - mean) * rstd * gg.w + bb.w);
        *(ulong1*)&y[i * 4] = *(ulong1*)o;
    }
}

// ---------------- RoPE on Q (in place, bf16) --------------------------------
__global__ void rope_q_kernel(u16* __restrict__ Q) {
    int idx = blockIdx.x * 256 + threadIdx.x;       // NROWS*24*32
    int j = idx & 31; int t = idx >> 5; int h = t % NHEADS; int row = t / NHEADS;
    int s = row & (S_LEN - 1);
    float freq = __expf(-(float)j * (9.210340371976184f / 64.f)); // 10000^(-j/64)
    float ang = (float)s * freq;
    float c = cosf(ang), si = sinf(ang);
    u16* p = Q + (size_t)row * DMODEL + h * 128 + 64;
    float x1 = bf2f(p[j]), x2 = bf2f(p[j + 32]);
    p[j]      = f2bf(x1 * c - x2 * si);
    p[j + 32] = f2bf(x2 * c + x1 * si);
}

// ---------------- RoPE on K_rope (from fp32 ckv -> bf16 kr) -----------------
__global__ void rope_k_kernel(const float* __restrict__ ckv, u16* __restrict__ kr) {
    int idx = blockIdx.x * 256 + threadIdx.x;       // NROWS*32
    int j = idx & 31; int row = idx >> 5;
    int s = row & (S_LEN - 1);
    float freq = __expf(-(float)j * (9.210340371976184f / 64.f));
    float ang = (float)s * freq;
    float c = cosf(ang), si = sinf(ang);
    const float* src = ckv + (size_t)row * CKV_W + KVPROJ;
    float x1 = src[j], x2 = src[j + 32];
    kr[(size_t)row * 64 + j]      = f2bf(x1 * c - x2 * si);
    kr[(size_t)row * 64 + j + 32] = f2bf(x2 * c + x1 * si);
}

// ---------------- pack K: Kp[bh][s][128] = nope | roped rope ----------------
__global__ __launch_bounds__(256) void pack_k(const u16* __restrict__ KVb,
                                              const u16* __restrict__ kr,
                                              u16* __restrict__ Kp) {
    int bh = blockIdx.y, bb = bh / NHEADS, h = bh % NHEADS;
    int s0 = blockIdx.x * 64;
    int t = threadIdx.x;
    size_t base = (size_t)bb * S_LEN;
#pragma unroll
    for (int it = 0; it < 4; ++it) {
        int j = it * 256 + t;
        int r = j >> 4, cb = (j & 15) * 8;
        int s = s0 + r;
        uint4 v;
        if (cb < 64) v = *(const uint4*)&KVb[(base + s) * UKV_N + h * 192 + cb];
        else         v = *(const uint4*)&kr[(base + s) * 64 + (cb - 64)];
        *(uint4*)&Kp[((size_t)bh * S_LEN + s) * 128 + cb] = v;
    }
}

// ---------------- pack V transposed: Vt[bh][d][s] ---------------------------
__global__ __launch_bounds__(256) void pack_v(const u16* __restrict__ KVb,
                                              u16* __restrict__ Vt) {
    __shared__ u16 tile[64][136];
    int bh = blockIdx.y, bb = bh / NHEADS, h = bh % NHEADS;
    int s0 = blockIdx.x * 64;
    int t = threadIdx.x;
    size_t base = (size_t)bb * S_LEN;
#pragma unroll
    for (int it = 0; it < 4; ++it) {
        int j = it * 256 + t;
        int r = j >> 4, cb = (j & 15) * 8;
        *(uint4*)&tile[r][cb] = *(const uint4*)&KVb[(base + s0 + r) * UKV_N + h * 192 + 64 + cb];
    }
    __syncthreads();
#pragma unroll
    for (int it = 0; it < 4; ++it) {
        int j = it * 256 + t;
        int d = j >> 3, sb = (j & 7) * 8;
        u16 tmp[8];
#pragma unroll
        for (int e = 0; e < 8; ++e) tmp[e] = tile[sb + e][d];
        *(uint4*)&Vt[((size_t)bh * 128 + d) * S_LEN + s0 + sb] = *(uint4*)tmp;
    }
}

// ---------------- GEMM 128x128, BK=32, dbuf + swizzle, XCD-chunked grid -----
template<bool OUT_BF16>
__global__ __launch_bounds__(256) void gemm_nt(const u16* __restrict__ A,
                                               const u16* __restrict__ B,
                                               void* __restrict__ Cv,
                                               int M, int N, int K, int nx) {
    __shared__ u16 a_lds[2][128][32];
    __shared__ u16 b_lds[2][128][32];
    int nwg = (int)gridDim.x;
    int bid = (int)blockIdx.x;
    int wg = (bid & 7) * (nwg >> 3) + (bid >> 3);
    int by = wg / nx, bx = wg - by * nx;
    int m0 = by * 128, n0 = bx * 128;
    int tid = threadIdx.x, lane = tid & 63, w = tid >> 6;
    int wm = w >> 1, wn = w & 1;
    int srow = lane >> 2;
    int kx = (lane >> 4) & 2;
    int scol = ((lane & 3) ^ kx) * 8;
    int r0 = w * 32 + srow, r1 = w * 32 + 16 + srow;
    const u16* A0 = A + (size_t)(m0 + r0) * K + scol;
    const u16* A1 = A + (size_t)(m0 + r1) * K + scol;
    int bn0 = n0 + r0; if (bn0 >= N) bn0 = N - 1;
    int bn1 = n0 + r1; if (bn1 >= N) bn1 = N - 1;
    const u16* B0 = B + (size_t)bn0 * K + scol;
    const u16* B1 = B + (size_t)bn1 * K + scol;
    char* aB = (char*)&a_lds[0][0][0];
    char* bB = (char*)&b_lds[0][0][0];
    int d0 = w * 2048, d1 = w * 2048 + 1024;
    int cb = ((lane >> 4) * 16) ^ ((lane & 8) << 2);

    f32x4 acc[4][4] = {};
    async16(A0, (u16*)(aB + d0)); async16(A1, (u16*)(aB + d1));
    async16(B0, (u16*)(bB + d0)); async16(B1, (u16*)(bB + d1));
    __syncthreads();
    int buf = 0;
    for (int kb = 0; kb < K; kb += 32) {
        if (kb + 32 < K) {
            int ob = (buf ^ 1) * 8192;
            async16(A0 + kb + 32, (u16*)(aB + ob + d0));
            async16(A1 + kb + 32, (u16*)(aB + ob + d1));
            async16(B0 + kb + 32, (u16*)(bB + ob + d0));
            async16(B1 + kb + 32, (u16*)(bB + ob + d1));
        }
        const char* ab = aB + buf * 8192;
        const char* bb = bB + buf * 8192;
        short8 af[4], bf[4];
#pragma unroll
        for (int i = 0; i < 4; ++i) {
            af[i] = *(const short8*)(ab + (wm * 64 + i * 16 + (lane & 15)) * 64 + cb);
            bf[i] = *(const short8*)(bb + (wn * 64 + i * 16 + (lane & 15)) * 64 + cb);
        }
#pragma unroll
        for (int i = 0; i < 4; ++i)
#pragma unroll
            for (int j = 0; j < 4; ++j)
                acc[i][j] = __builtin_amdgcn_mfma_f32_16x16x32_bf16(af[i], bf[j], acc[i][j], 0, 0, 0);
        __syncthreads();
        buf ^= 1;
    }
#pragma unroll
    for (int i = 0; i < 4; ++i) {
        int row = m0 + wm * 64 + i * 16 + ((lane >> 4) << 2);
#pragma unroll
        for (int j = 0; j < 4; ++j) {
            int col = n0 + wn * 64 + j * 16 + (lane & 15);
            if (col < N) {
#pragma unroll
                for (int r = 0; r < 4; ++r) {
                    if (OUT_BF16) ((u16*)Cv)[(size_t)(row + r) * N + col] = f2bf(acc[i][j][r]);
                    else          ((float*)Cv)[(size_t)(row + r) * N + col] = acc[i][j][r];
                }
            }
        }
    }
}

// ---------------- GEMM 256x256, BK=32, 4-slot rotation + counted vmcnt ------
// Pipelined (T3/T4): K-tile k lives in LDS slot k&3. Slot stride is 32768 B
// ([2][256][32] u16 = 16 KB A + 16 KB B). [R12 bug: stride was 65536 -> slots
// 2,3 out of bounds -> zero output. Fixed.]
// Group g: ph0 stages A(g+3) + computes mh=0; ph1 stages B(g+3) + computes
// mh=1; group-end s_waitcnt vmcnt(8) (never 0 until tail) + s_barrier.
// WAR-safe: slot (g+3)&3's last reader was group g-1, barrier-separated.
// Requires M%256==0, N%256==0, K%32==0, K/32>=4.
template<bool OUT_BF16>
__global__ __launch_bounds__(512, 2) void gemm_nt8(const u16* __restrict__ A,
                                                   const u16* __restrict__ B,
                                                   void* __restrict__ Cv,
                                                   int M, int N, int K, int nx) {
    __shared__ u16 lds[4][2][256][32];   // [slot][mat][row][col], 128 KB
    int nwg = (int)gridDim.x;
    int bid = (int)blockIdx.x;
    int wg = (bid & 7) * (nwg >> 3) + (bid >> 3);
    int by = wg / nx, bx = wg - by * nx;
    int m0 = by * 256, n0 = bx * 256;
    int tid = threadIdx.x, lane = tid & 63, w = tid >> 6;   // 8 waves
    int wm = w >> 2, wn = w & 3;                             // 2 x 4
    char* L = (char*)&lds[0][0][0][0];

    int ra = tid >> 2,          ca = ((tid & 3) ^ (ra & 3)) * 8;
    int rb = (tid + 512) >> 2,  cbs = (((tid + 512) & 3) ^ (rb & 3)) * 8;
    const u16* Asrc0 = A + (size_t)(m0 + ra) * K + ca;
    const u16* Asrc1 = A + (size_t)(m0 + rb) * K + cbs;
    const u16* Bsrc0 = B + (size_t)(n0 + ra) * K + ca;
    const u16* Bsrc1 = B + (size_t)(n0 + rb) * K + cbs;
    int dst0 = (w * 64) * 16;            // + lane*16 implicit
    int dst1 = 8192 + (w * 64) * 16;

    int nkt = K >> 5;
    f32x4 acc[8][4] = {};

    // prologue: stage K-tiles 0,1,2 (A then B each; 12 loads/thread)
#pragma unroll
    for (int k = 0; k < 3; ++k) {
        int sb_ = (k & 3) * 32768;
        async16(Asrc0 + k * 32, (u16*)(L + sb_ + dst0));
        async16(Asrc1 + k * 32, (u16*)(L + sb_ + dst1));
        async16(Bsrc0 + k * 32, (u16*)(L + sb_ + 16384 + dst0));
        async16(Bsrc1 + k * 32, (u16*)(L + sb_ + 16384 + dst1));
    }
    asm volatile("s_waitcnt vmcnt(8)" ::: "memory");   // K-tile 0 landed
    __builtin_amdgcn_s_barrier();

    for (int g = 0; g < nkt; ++g) {
        int slot = g & 3;
        const char* As = L + slot * 32768;
        const char* Bs = L + slot * 32768 + 16384;
        bool more = (g + 3 < nkt);
        int s2 = ((g + 3) & 3) * 32768;
        size_t koff = (size_t)(g + 3) * 32;

        short8 bf[4];
        // ---- phase 0: stage A(g+3); read B frags + A quadrant mh=0; 16 MFMA
        if (more) {
            async16(Asrc0 + koff, (u16*)(L + s2 + dst0));
            async16(Asrc1 + koff, (u16*)(L + s2 + dst1));
        }
        {
            short8 af[4];
#pragma unroll
            for (int f = 0; f < 4; ++f) {
                int R = wm * 128 + f * 16 + (lane & 15);
                af[f] = *(const short8*)(As + R * 64 + (((lane >> 4) * 16) ^ ((R & 3) << 4)));
            }
#pragma unroll
            for (int nf = 0; nf < 4; ++nf) {
                int R = wn * 64 + nf * 16 + (lane & 15);
                bf[nf] = *(const short8*)(Bs + R * 64 + (((lane >> 4) * 16) ^ ((R & 3) << 4)));
            }
            __builtin_amdgcn_sched_barrier(0);
            __builtin_amdgcn_s_barrier();
            __builtin_amdgcn_s_setprio(1);
#pragma unroll
            for (int f = 0; f < 4; ++f)
#pragma unroll
                for (int nf = 0; nf < 4; ++nf)
                    acc[f][nf] = __builtin_amdgcn_mfma_f32_16x16x32_bf16(af[f], bf[nf], acc[f][nf], 0, 0, 0);
            __builtin_amdgcn_s_setprio(0);
        }
        // ---- phase 1: stage B(g+3); read A quadrant mh=1; 16 MFMA
        if (more) {
            async16(Bsrc0 + koff, (u16*)(L + s2 + 16384 + dst0));
            async16(Bsrc1 + koff, (u16*)(L + s2 + 16384 + dst1));
        }
        {
            short8 af[4];
#pragma unroll
            for (int f = 0; f < 4; ++f) {
                int R = wm * 128 + 64 + f * 16 + (lane & 15);
                af[f] = *(const short8*)(As + R * 64 + (((lane >> 4) * 16) ^ ((R & 3) << 4)));
            }
            __builtin_amdgcn_sched_barrier(0);
            __builtin_amdgcn_s_barrier();
            __builtin_amdgcn_s_setprio(1);
#pragma unroll
            for (int f = 0; f < 4; ++f)
#pragma unroll
                for (int nf = 0; nf < 4; ++nf)
                    acc[4 + f][nf] = __builtin_amdgcn_mfma_f32_16x16x32_bf16(af[f], bf[nf], acc[4 + f][nf], 0, 0, 0);
            __builtin_amdgcn_s_setprio(0);
        }
        // ---- group end: counted vmcnt (never 0 until tail), then barrier
        if (more) asm volatile("s_waitcnt vmcnt(8)" ::: "memory");
        else      asm volatile("s_waitcnt vmcnt(0)" ::: "memory");
        __builtin_amdgcn_s_barrier();
    }

#pragma unroll
    for (int mi = 0; mi < 8; ++mi) {
        int row = m0 + wm * 128 + mi * 16 + ((lane >> 4) << 2);
#pragma unroll
        for (int nf = 0; nf < 4; ++nf) {
            int col = n0 + wn * 64 + nf * 16 + (lane & 15);
#pragma unroll
            for (int r = 0; r < 4; ++r) {
                if (OUT_BF16) ((u16*)Cv)[(size_t)(row + r) * N + col] = f2bf(acc[mi][nf][r]);
                else          ((float*)Cv)[(size_t)(row + r) * N + col] = acc[mi][nf][r];
            }
        }
    }
}

// ---------------- Flash attention: paired causal blocks, XCD-clustered ------
// (R11 version verbatim)
__global__ __launch_bounds__(256) void attn_kernel(const u16* __restrict__ Qb,
                                                   const u16* __restrict__ Kp,
                                                   const u16* __restrict__ Vt,
                                                   u16* __restrict__ AO) {
    __shared__ u16 k_lds[64][128];     // 16 KB
    __shared__ u16 v_lds[128][64];     // 16 KB
    __shared__ u16 p_lds[4][16][64];   // 8 KB (XOR-swizzled) -> total 40960 B
    int bid = blockIdx.x;
    int jj = bid >> 3;
    int bh = (bid & 7) * 6 + (jj >> 4);          // all 16 blocks of a head on one XCD
    int bx = jj & 15;
    int bb = bh / NHEADS, h = bh % NHEADS;
    int tid = threadIdx.x, lane = tid & 63, w = tid >> 6;
    size_t base = (size_t)bb * S_LEN;
    size_t bhS = (size_t)bh * S_LEN;

    const char* Kbyte = (const char*)Kp;
    const char* Vbyte = (const char*)Vt;
    char* kB = (char*)&k_lds[0][0];
    char* vB = (char*)&v_lds[0][0];
    char* pB = (char*)&p_lds[0][0][0] + w * 2048;   // per-wave 16x128B
    size_t ksrc[4], vsrc[4];
    int kd[4];
#pragma unroll
    for (int is = 0; is < 4; ++is) {
        int j = is * 256 + tid;
        int r = j >> 4;
        int cbs = ((j & 15) * 16) ^ ((r & 7) << 4);
        ksrc[is] = (bhS + r) * 256 + cbs;
        int d = j >> 3;
        int kbs = (((j & 7) ^ (d & 7)) * 16);
        vsrc[is] = ((size_t)bh * 128 + d) * (S_LEN * 2) + kbs;
        kd[is] = (is * 256 + w * 64) * 16;
    }

    for (int seg = 0; seg < 2; ++seg) {
        int qx = seg == 0 ? (31 - bx) : bx;      // long segment first
        int q0 = qx * 64;

        short8 qf[4];
        {
            int qrow = q0 + w * 16 + (lane & 15);
            const u16* qp = Qb + (base + qrow) * DMODEL + h * 128 + ((lane >> 4) * 8);
#pragma unroll
            for (int ks = 0; ks < 4; ++ks) qf[ks] = *(const short8*)(qp + ks * 32);
        }

        f32x4 acc_o[8] = {};
        float m_run[4], l_run[4];
#pragma unroll
        for (int r = 0; r < 4; ++r) { m_run[r] = -1e30f; l_run[r] = 0.f; }

        int ntiles = qx + 1;
        for (int t = 0; t < ntiles; ++t) {
            size_t kv0 = (size_t)t * 64;
#pragma unroll
            for (int is = 0; is < 4; ++is)
                async16((const u16*)(Kbyte + ksrc[is] + kv0 * 256), (u16*)(kB + kd[is]));
#pragma unroll
            for (int is = 0; is < 4; ++is)
                async16((const u16*)(Vbyte + vsrc[is] + kv0 * 2), (u16*)(vB + kd[is]));
            __syncthreads();

            f32x4 sc[4];
            __builtin_amdgcn_s_setprio(1);
#pragma unroll
            for (int nb = 0; nb < 4; ++nb) {
                f32x4 a = {};
                int row = nb * 16 + (lane & 15);
                const char* kb_ = kB + row * 256;
                int x = (row & 7) << 4;
#pragma unroll
                for (int ks = 0; ks < 4; ++ks) {
                    short8 kf = *(const short8*)(kb_ + ((ks * 64 + (lane >> 4) * 16) ^ x));
                    a = __builtin_amdgcn_mfma_f32_16x16x32_bf16(qf[ks], kf, a, 0, 0, 0);
                }
                sc[nb] = a;
            }
            __builtin_amdgcn_s_setprio(0);

            if (t == qx) {     // diagonal tile: causal mask
                int kvb = t * 64;
                int qg = q0 + w * 16 + ((lane >> 4) << 2);
#pragma unroll
                for (int nb = 0; nb < 4; ++nb) {
                    int kc = kvb + nb * 16 + (lane & 15);
#pragma unroll
                    for (int r = 0; r < 4; ++r)
                        if (kc > qg + r) sc[nb][r] = -1e30f;
                }
            }
            float rmax[4];
#pragma unroll
            for (int r = 0; r < 4; ++r)
                rmax[r] = fmaxf(fmaxf(sc[0][r], sc[1][r]), fmaxf(sc[2][r], sc[3][r]));
#pragma unroll
            for (int off = 1; off < 16; off <<= 1)
#pragma unroll
                for (int r = 0; r < 4; ++r) rmax[r] = fmaxf(rmax[r], __shfl_xor(rmax[r], off));

            bool ok = (rmax[0] <= m_run[0]) & (rmax[1] <= m_run[1]) &
                      (rmax[2] <= m_run[2]) & (rmax[3] <= m_run[3]);
            if (!__all(ok)) {
                float fac[4];
#pragma unroll
                for (int r = 0; r < 4; ++r) {
                    float mnew = fmaxf(m_run[r], rmax[r]);
                    fac[r] = __expf(m_run[r] - mnew);
                    m_run[r] = mnew;
                    l_run[r] *= fac[r];
                }
#pragma unroll
                for (int db = 0; db < 8; ++db)
#pragma unroll
                    for (int r = 0; r < 4; ++r) acc_o[db][r] *= fac[r];
            }
#pragma unroll
            for (int nb = 0; nb < 4; ++nb)
#pragma unroll
                for (int r = 0; r < 4; ++r) {
                    float p = __expf(sc[nb][r] - m_run[r]);
                    sc[nb][r] = p; l_run[r] += p;
                }

#pragma unroll
            for (int nb = 0; nb < 4; ++nb)
#pragma unroll
                for (int r = 0; r < 4; ++r) {
                    int row = ((lane >> 4) << 2) + r;
                    int cby = (nb * 32 + (lane & 15) * 2) ^ ((row & 7) << 4);
                    *(u16*)(pB + row * 128 + cby) = f2bf(sc[nb][r]);
                }
            __builtin_amdgcn_sched_barrier(0);
            __builtin_amdgcn_s_setprio(1);
#pragma unroll
            for (int ks = 0; ks < 2; ++ks) {
                int prow = lane & 15;
                short8 pf = *(const short8*)(pB + prow * 128 +
                                ((ks * 64 + (lane >> 4) * 16) ^ ((prow & 7) << 4)));
#pragma unroll
                for (int db = 0; db < 8; ++db) {
                    int row = db * 16 + (lane & 15);
                    const char* vb_ = vB + row * 128;
                    short8 vf = *(const short8*)(vb_ + ((ks * 64 + (lane >> 4) * 16) ^ ((row & 7) << 4)));
                    acc_o[db] = __builtin_amdgcn_mfma_f32_16x16x32_bf16(pf, vf, acc_o[db], 0, 0, 0);
                }
            }
            __builtin_amdgcn_s_setprio(0);
            __syncthreads();
        }

#pragma unroll
        for (int off = 1; off < 16; off <<= 1)
#pragma unroll
            for (int r = 0; r < 4; ++r) l_run[r] += __shfl_xor(l_run[r], off);

        int orow = q0 + w * 16 + ((lane >> 4) << 2);
#pragma unroll
        for (int db = 0; db < 8; ++db)
#pragma unroll
            for (int r = 0; r < 4; ++r) {
                float o = acc_o[db][r] / l_run[r];
                AO[(base + orow + r) * DMODEL + h * 128 + db * 16 + (lane & 15)] = f2bf(o);
            }
    }
}

// ---------------------------------------------------------------------------
extern "C" void kernel_launch(void* const* d_in, const int* in_sizes, int n_in,
                              void* d_out, int out_size, void* d_ws, size_t ws_size,
                              hipStream_t stream) {
    (void)in_sizes; (void)n_in; (void)out_size; (void)ws_size;
    const float* x      = (const float*)d_in[0];
    const float* W_dq   = (const float*)d_in[1];
    const float* W_uq   = (const float*)d_in[2];
    const float* q_ln_w = (const float*)d_in[3];
    const float* q_ln_b = (const float*)d_in[4];
    const float* W_dkv  = (const float*)d_in[5];
    const float* W_ukv  = (const float*)d_in[6];
    const float* kv_ln_w= (const float*)d_in[7];
    const float* kv_ln_b= (const float*)d_in[8];
    const float* W_o    = (const float*)d_in[9];

    float* out = (float*)d_out;
    float* ckv = out + (size_t)NROWS * DMODEL;   // output #2 region

    char* ws = (char*)d_ws;
    const size_t OFF_WDQT  = 0;
    const size_t OFF_WUQT  = 9437184;
    const size_t OFF_WDKVT = 18874368;
    const size_t OFF_WUKVT = 31850496;
    const size_t OFF_WO    = 50724864;
    const size_t OFF_XB    = 69599232;
    const size_t OFF_QB    = 94765056;
    const size_t OFF_KVB   = 119930880;
    const size_t OFF_KR    = 157679616;
    const size_t OFF_SLABA = 158203904;  // t0 fp32, later ao bf16
    const size_t OFF_SLABB = 183369728;  // cq bf16, later kvl bf16
    const size_t OFF_KP    = 0;          // over Wdq_t/Wuq_t/Wdkv_t (dead), 25.2MB
    const size_t OFF_VT    = OFF_XB;     // over xb (dead), 25.2MB

    u16* Wdq_t  = (u16*)(ws + OFF_WDQT);
    u16* Wuq_t  = (u16*)(ws + OFF_WUQT);
    u16* Wdkv_t = (u16*)(ws + OFF_WDKVT);
    u16* Wukv_t = (u16*)(ws + OFF_WUKVT);
    u16* Wo_b   = (u16*)(ws + OFF_WO);
    u16* xb     = (u16*)(ws + OFF_XB);
    u16* qb     = (u16*)(ws + OFF_QB);
    u16* KVb    = (u16*)(ws + OFF_KVB);
    u16* kr     = (u16*)(ws + OFF_KR);
    float* t0   = (float*)(ws + OFF_SLABA);
    u16* ao     = (u16*)(ws + OFF_SLABA);
    u16* cq     = (u16*)(ws + OFF_SLABB);
    u16* kvl    = (u16*)(ws + OFF_SLABB);
    u16* Kp     = (u16*)(ws + OFF_KP);
    u16* Vt     = (u16*)(ws + OFF_VT);

    const float SCALE = 0.08838834764831845f;    // 1/sqrt(128), folded into W_uq

    // weight prep
    transpose_bf16<<<dim3(QPROJ / 32, DMODEL / 32), 256, 0, stream>>>(W_dq,  Wdq_t,  DMODEL, QPROJ, 1.0f);
    transpose_bf16<<<dim3(DMODEL / 32, QPROJ / 32), 256, 0, stream>>>(W_uq,  Wuq_t,  QPROJ, DMODEL, SCALE);
    transpose_bf16<<<dim3(CKV_W / 32, DMODEL / 32), 256, 0, stream>>>(W_dkv, Wdkv_t, DMODEL, CKV_W, 1.0f);
    transpose_bf16<<<dim3(UKV_N / 32, KVPROJ / 32), 256, 0, stream>>>(W_ukv, Wukv_t, KVPROJ, UKV_N, 1.0f);
    conv_bf16<<<9216, 256, 0, stream>>>(W_o, Wo_b, DMODEL * DMODEL);
    conv_bf16<<<12288, 256, 0, stream>>>(x, xb, NROWS * DMODEL);

    // q path
    gemm_nt<false><<<(QPROJ / 128) * (NROWS / 128), 256, 0, stream>>>(xb, Wdq_t, t0, NROWS, QPROJ, DMODEL, QPROJ / 128);
    ln_kernel<<<NROWS, 256, 0, stream>>>(t0, QPROJ, q_ln_w, q_ln_b, cq, QPROJ);
    gemm_nt8<true><<<(DMODEL / 256) * (NROWS / 256), 512, 0, stream>>>(cq, Wuq_t, qb, NROWS, DMODEL, QPROJ, DMODEL / 256);
    rope_q_kernel<<<12288, 256, 0, stream>>>(qb);

    // kv path
    gemm_nt<false><<<17 * (NROWS / 128), 256, 0, stream>>>(xb, Wdkv_t, ckv, NROWS, CKV_W, DMODEL, 17);
    ln_kernel<<<NROWS, 256, 0, stream>>>(ckv, CKV_W, kv_ln_w, kv_ln_b, kvl, KVPROJ);
    rope_k_kernel<<<512, 256, 0, stream>>>(ckv, kr);
    gemm_nt8<true><<<(UKV_N / 256) * (NROWS / 256), 512, 0, stream>>>(kvl, Wukv_t, KVb, NROWS, UKV_N, KVPROJ, UKV_N / 256);

    // pack K/V for attention (Wdq_t/Wuq_t/Wdkv_t and xb are dead now)
    pack_k<<<dim3(S_LEN / 64, 2 * NHEADS), 256, 0, stream>>>(KVb, kr, Kp);
    pack_v<<<dim3(S_LEN / 64, 2 * NHEADS), 256, 0, stream>>>(KVb, Vt);

    // attention (768 uniform paired blocks, XCD head-clustered)
    attn_kernel<<<768, 256, 0, stream>>>(qb, Kp, Vt, ao);

    // output projection
    gemm_nt8<false><<<(DMODEL / 256) * (NROWS / 256), 512, 0, stream>>>(ao, Wo_b, out, NROWS, DMODEL, DMODEL, DMODEL / 256);
}

// Round 14
// 633.712 us; speedup vs baseline: 1.0282x; 1.0282x over previous
//
#include <hip/hip_runtime.h>

typedef unsigned short u16;
typedef __attribute__((ext_vector_type(8))) short short8;
typedef __attribute__((ext_vector_type(4))) float f32x4;

#define NROWS   4096     // B*S
#define S_LEN   2048
#define NHEADS  24
#define DMODEL  3072
#define QPROJ   1536
#define KVPROJ  2048
#define CKV_W   2112     // KVPROJ + 64 rope
#define UKV_N   4608     // DMODEL + 24*64

__device__ __forceinline__ float bf2f(u16 v) {
    unsigned u = ((unsigned)v) << 16; float f; __builtin_memcpy(&f, &u, 4); return f;
}
__device__ __forceinline__ u16 f2bf(float f) {
    unsigned u; __builtin_memcpy(&u, &f, 4);
    u = (u + 0x7FFFu + ((u >> 16) & 1u)) >> 16; return (u16)u;
}
__device__ __forceinline__ u16 f2bf_trunc(float f) {
    unsigned u; __builtin_memcpy(&u, &f, 4);
    return (u16)(u >> 16);
}
__device__ __forceinline__ void async16(const u16* g, u16* l) {
    __builtin_amdgcn_global_load_lds((const __attribute__((address_space(1))) unsigned int*)g,
                                     (__attribute__((address_space(3))) unsigned int*)l,
                                     16, 0, 0);
}

// ---------------- elementwise convert fp32 -> bf16 (vectorized) -------------
__global__ void conv_bf16(const float* __restrict__ X, u16* __restrict__ Y, int n) {
    int i = (blockIdx.x * 256 + threadIdx.x) * 4;
    if (i >= n) return;
    float4 v = *(const float4*)(X + i);
    Y[i+0] = f2bf(v.x); Y[i+1] = f2bf(v.y); Y[i+2] = f2bf(v.z); Y[i+3] = f2bf(v.w);
}

// ---------------- transpose + convert + scale: W (K x N) -> WT (N x K) bf16 -
__global__ void transpose_bf16(const float* __restrict__ W, u16* __restrict__ WT,
                               int K, int N, float scale) {
    __shared__ float t[32][33];
    int nb = blockIdx.x * 32, kb = blockIdx.y * 32;
    int c = threadIdx.x & 31, rq = threadIdx.x >> 5;
#pragma unroll
    for (int i = 0; i < 4; ++i) {
        int r = rq * 4 + i;
        t[r][c] = W[(size_t)(kb + r) * N + nb + c];
    }
    __syncthreads();
#pragma unroll
    for (int i = 0; i < 4; ++i) {
        int r = rq * 4 + i;
        WT[(size_t)(nb + r) * K + kb + c] = f2bf(t[c][r] * scale);
    }
}

// ---------------- LayerNorm (fp32 in, bf16 out), float4-vectorized ----------
__global__ __launch_bounds__(256) void ln_kernel(const float* __restrict__ X, int ldx,
                                                 const float* __restrict__ g,
                                                 const float* __restrict__ b,
                                                 u16* __restrict__ Y, int W) {
    int row = blockIdx.x;
    const float4* x4 = (const float4*)(X + (size_t)row * ldx);
    int W4 = W >> 2;
    float s = 0.f, s2 = 0.f;
    for (int i = threadIdx.x; i < W4; i += 256) {
        float4 v = x4[i];
        s += v.x + v.y + v.z + v.w;
        s2 += v.x * v.x + v.y * v.y + v.z * v.z + v.w * v.w;
    }
#pragma unroll
    for (int off = 32; off >= 1; off >>= 1) { s += __shfl_xor(s, off); s2 += __shfl_xor(s2, off); }
    __shared__ float red[8];
    int w = threadIdx.x >> 6;
    if ((threadIdx.x & 63) == 0) { red[w] = s; red[4 + w] = s2; }
    __syncthreads();
    s  = red[0] + red[1] + red[2] + red[3];
    s2 = red[4] + red[5] + red[6] + red[7];
    float mean = s / W;
    float var  = s2 / W - mean * mean;
    float rstd = rsqrtf(var + 1e-5f);
    const float4* g4 = (const float4*)g;
    const float4* b4 = (const float4*)b;
    u16* y = Y + (size_t)row * W;
    for (int i = threadIdx.x; i < W4; i += 256) {
        float4 v = x4[i], gg = g4[i], bb = b4[i];
        u16 o[4];
        o[0] = f2bf((v.x - mean) * rstd * gg.x + bb.x);
        o[1] = f2bf((v.y - mean) * rstd * gg.y + bb.y);
        o[2] = f2bf((v.z - mean) * rstd * gg.z + bb.z);
        o[3] = f2bf((v.w - mean) * rstd * gg.w + bb.w);
        *(ulong1*)&y[i * 4] = *(ulong1*)o;
    }
}

// ---------------- LayerNorm (bf16 in, bf16 out), 4-elem vectorized ----------
__global__ __launch_bounds__(256) void ln_bf16_kernel(const u16* __restrict__ X,
                                                      const float* __restrict__ g,
                                                      const float* __restrict__ b,
                                                      u16* __restrict__ Y, int W) {
    int row = blockIdx.x;
    const u16* x = X + (size_t)row * W;
    int W4 = W >> 2;
    float s = 0.f, s2 = 0.f;
    for (int i = threadIdx.x; i < W4; i += 256) {
        ushort4 v = *(const ushort4*)(x + i * 4);
        float a0 = bf2f(v.x), a1 = bf2f(v.y), a2 = bf2f(v.z), a3 = bf2f(v.w);
        s += a0 + a1 + a2 + a3;
        s2 += a0 * a0 + a1 * a1 + a2 * a2 + a3 * a3;
    }
#pragma unroll
    for (int off = 32; off >= 1; off >>= 1) { s += __shfl_xor(s, off); s2 += __shfl_xor(s2, off); }
    __shared__ float red[8];
    int w = threadIdx.x >> 6;
    if ((threadIdx.x & 63) == 0) { red[w] = s; red[4 + w] = s2; }
    __syncthreads();
    s  = red[0] + red[1] + red[2] + red[3];
    s2 = red[4] + red[5] + red[6] + red[7];
    float mean = s / W;
    float var  = s2 / W - mean * mean;
    float rstd = rsqrtf(var + 1e-5f);
    const float4* g4 = (const float4*)g;
    const float4* b4 = (const float4*)b;
    u16* y = Y + (size_t)row * W;
    for (int i = threadIdx.x; i < W4; i += 256) {
        ushort4 v = *(const ushort4*)(x + i * 4);
        float4 gg = g4[i], bb = b4[i];
        u16 o[4];
        o[0] = f2bf((bf2f(v.x) - mean) * rstd * gg.x + bb.x);
        o[1] = f2bf((bf2f(v.y) - mean) * rstd * gg.y + bb.y);
        o[2] = f2bf((bf2f(v.z) - mean) * rstd * gg.z + bb.z);
        o[3] = f2bf((bf2f(v.w) - mean) * rstd * gg.w + bb.w);
        *(ulong1*)&y[i * 4] = *(ulong1*)o;
    }
}

// ---------------- RoPE on Q (in place, bf16) --------------------------------
__global__ void rope_q_kernel(u16* __restrict__ Q) {
    int idx = blockIdx.x * 256 + threadIdx.x;       // NROWS*24*32
    int j = idx & 31; int t = idx >> 5; int h = t % NHEADS; int row = t / NHEADS;
    int s = row & (S_LEN - 1);
    float freq = __expf(-(float)j * (9.210340371976184f / 64.f)); // 10000^(-j/64)
    float ang = (float)s * freq;
    float c = cosf(ang), si = sinf(ang);
    u16* p = Q + (size_t)row * DMODEL + h * 128 + 64;
    float x1 = bf2f(p[j]), x2 = bf2f(p[j + 32]);
    p[j]      = f2bf(x1 * c - x2 * si);
    p[j + 32] = f2bf(x2 * c + x1 * si);
}

// ---------------- RoPE on K_rope (from fp32 ckv -> bf16 kr) -----------------
__global__ void rope_k_kernel(const float* __restrict__ ckv, u16* __restrict__ kr) {
    int idx = blockIdx.x * 256 + threadIdx.x;       // NROWS*32
    int j = idx & 31; int row = idx >> 5;
    int s = row & (S_LEN - 1);
    float freq = __expf(-(float)j * (9.210340371976184f / 64.f));
    float ang = (float)s * freq;
    float c = cosf(ang), si = sinf(ang);
    const float* src = ckv + (size_t)row * CKV_W + KVPROJ;
    float x1 = src[j], x2 = src[j + 32];
    kr[(size_t)row * 64 + j]      = f2bf(x1 * c - x2 * si);
    kr[(size_t)row * 64 + j + 32] = f2bf(x2 * c + x1 * si);
}

// ---------------- pack K: Kp[bh][s][128] = nope | roped rope ----------------
__global__ __launch_bounds__(256) void pack_k(const u16* __restrict__ KVb,
                                              const u16* __restrict__ kr,
                                              u16* __restrict__ Kp) {
    int bh = blockIdx.y, bb = bh / NHEADS, h = bh % NHEADS;
    int s0 = blockIdx.x * 64;
    int t = threadIdx.x;
    size_t base = (size_t)bb * S_LEN;
#pragma unroll
    for (int it = 0; it < 4; ++it) {
        int j = it * 256 + t;
        int r = j >> 4, cb = (j & 15) * 8;
        int s = s0 + r;
        uint4 v;
        if (cb < 64) v = *(const uint4*)&KVb[(base + s) * UKV_N + h * 192 + cb];
        else         v = *(const uint4*)&kr[(base + s) * 64 + (cb - 64)];
        *(uint4*)&Kp[((size_t)bh * S_LEN + s) * 128 + cb] = v;
    }
}

// ---------------- pack V transposed: Vt[bh][d][s] ---------------------------
__global__ __launch_bounds__(256) void pack_v(const u16* __restrict__ KVb,
                                              u16* __restrict__ Vt) {
    __shared__ u16 tile[64][136];
    int bh = blockIdx.y, bb = bh / NHEADS, h = bh % NHEADS;
    int s0 = blockIdx.x * 64;
    int t = threadIdx.x;
    size_t base = (size_t)bb * S_LEN;
#pragma unroll
    for (int it = 0; it < 4; ++it) {
        int j = it * 256 + t;
        int r = j >> 4, cb = (j & 15) * 8;
        *(uint4*)&tile[r][cb] = *(const uint4*)&KVb[(base + s0 + r) * UKV_N + h * 192 + 64 + cb];
    }
    __syncthreads();
#pragma unroll
    for (int it = 0; it < 4; ++it) {
        int j = it * 256 + t;
        int d = j >> 3, sb = (j & 7) * 8;
        u16 tmp[8];
#pragma unroll
        for (int e = 0; e < 8; ++e) tmp[e] = tile[sb + e][d];
        *(uint4*)&Vt[((size_t)bh * 128 + d) * S_LEN + s0 + sb] = *(uint4*)tmp;
    }
}

// ---------------- GEMM 128x128, BK=32, dbuf + swizzle, XCD-chunked grid -----
template<bool OUT_BF16>
__global__ __launch_bounds__(256) void gemm_nt(const u16* __restrict__ A,
                                               const u16* __restrict__ B,
                                               void* __restrict__ Cv,
                                               int M, int N, int K, int nx) {
    __shared__ u16 a_lds[2][128][32];
    __shared__ u16 b_lds[2][128][32];
    int nwg = (int)gridDim.x;
    int bid = (int)blockIdx.x;
    int wg = (bid & 7) * (nwg >> 3) + (bid >> 3);
    int by = wg / nx, bx = wg - by * nx;
    int m0 = by * 128, n0 = bx * 128;
    int tid = threadIdx.x, lane = tid & 63, w = tid >> 6;
    int wm = w >> 1, wn = w & 1;
    int srow = lane >> 2;
    int kx = (lane >> 4) & 2;
    int scol = ((lane & 3) ^ kx) * 8;
    int r0 = w * 32 + srow, r1 = w * 32 + 16 + srow;
    const u16* A0 = A + (size_t)(m0 + r0) * K + scol;
    const u16* A1 = A + (size_t)(m0 + r1) * K + scol;
    int bn0 = n0 + r0; if (bn0 >= N) bn0 = N - 1;
    int bn1 = n0 + r1; if (bn1 >= N) bn1 = N - 1;
    const u16* B0 = B + (size_t)bn0 * K + scol;
    const u16* B1 = B + (size_t)bn1 * K + scol;
    char* aB = (char*)&a_lds[0][0][0];
    char* bB = (char*)&b_lds[0][0][0];
    int d0 = w * 2048, d1 = w * 2048 + 1024;
    int cb = ((lane >> 4) * 16) ^ ((lane & 8) << 2);

    f32x4 acc[4][4] = {};
    async16(A0, (u16*)(aB + d0)); async16(A1, (u16*)(aB + d1));
    async16(B0, (u16*)(bB + d0)); async16(B1, (u16*)(bB + d1));
    __syncthreads();
    int buf = 0;
    for (int kb = 0; kb < K; kb += 32) {
        if (kb + 32 < K) {
            int ob = (buf ^ 1) * 8192;
            async16(A0 + kb + 32, (u16*)(aB + ob + d0));
            async16(A1 + kb + 32, (u16*)(aB + ob + d1));
            async16(B0 + kb + 32, (u16*)(bB + ob + d0));
            async16(B1 + kb + 32, (u16*)(bB + ob + d1));
        }
        const char* ab = aB + buf * 8192;
        const char* bb = bB + buf * 8192;
        short8 af[4], bf[4];
#pragma unroll
        for (int i = 0; i < 4; ++i) {
            af[i] = *(const short8*)(ab + (wm * 64 + i * 16 + (lane & 15)) * 64 + cb);
            bf[i] = *(const short8*)(bb + (wn * 64 + i * 16 + (lane & 15)) * 64 + cb);
        }
#pragma unroll
        for (int i = 0; i < 4; ++i)
#pragma unroll
            for (int j = 0; j < 4; ++j)
                acc[i][j] = __builtin_amdgcn_mfma_f32_16x16x32_bf16(af[i], bf[j], acc[i][j], 0, 0, 0);
        __syncthreads();
        buf ^= 1;
    }
#pragma unroll
    for (int i = 0; i < 4; ++i) {
        int row = m0 + wm * 64 + i * 16 + ((lane >> 4) << 2);
#pragma unroll
        for (int j = 0; j < 4; ++j) {
            int col = n0 + wn * 64 + j * 16 + (lane & 15);
            if (col < N) {
#pragma unroll
                for (int r = 0; r < 4; ++r) {
                    if (OUT_BF16) ((u16*)Cv)[(size_t)(row + r) * N + col] = f2bf(acc[i][j][r]);
                    else          ((float*)Cv)[(size_t)(row + r) * N + col] = acc[i][j][r];
                }
            }
        }
    }
}

// ---------------- Flash attention: paired causal blocks, XCD-clustered ------
// (R11 structure; P stored with truncation instead of RNE rounding)
__global__ __launch_bounds__(256) void attn_kernel(const u16* __restrict__ Qb,
                                                   const u16* __restrict__ Kp,
                                                   const u16* __restrict__ Vt,
                                                   u16* __restrict__ AO) {
    __shared__ u16 k_lds[64][128];     // 16 KB
    __shared__ u16 v_lds[128][64];     // 16 KB
    __shared__ u16 p_lds[4][16][64];   // 8 KB (XOR-swizzled) -> total 40960 B
    int bid = blockIdx.x;
    int jj = bid >> 3;
    int bh = (bid & 7) * 6 + (jj >> 4);          // all 16 blocks of a head on one XCD
    int bx = jj & 15;
    int bb = bh / NHEADS, h = bh % NHEADS;
    int tid = threadIdx.x, lane = tid & 63, w = tid >> 6;
    size_t base = (size_t)bb * S_LEN;
    size_t bhS = (size_t)bh * S_LEN;

    const char* Kbyte = (const char*)Kp;
    const char* Vbyte = (const char*)Vt;
    char* kB = (char*)&k_lds[0][0];
    char* vB = (char*)&v_lds[0][0];
    char* pB = (char*)&p_lds[0][0][0] + w * 2048;   // per-wave 16x128B
    size_t ksrc[4], vsrc[4];
    int kd[4];
#pragma unroll
    for (int is = 0; is < 4; ++is) {
        int j = is * 256 + tid;
        int r = j >> 4;
        int cbs = ((j & 15) * 16) ^ ((r & 7) << 4);
        ksrc[is] = (bhS + r) * 256 + cbs;
        int d = j >> 3;
        int kbs = (((j & 7) ^ (d & 7)) * 16);
        vsrc[is] = ((size_t)bh * 128 + d) * (S_LEN * 2) + kbs;
        kd[is] = (is * 256 + w * 64) * 16;
    }

    for (int seg = 0; seg < 2; ++seg) {
        int qx = seg == 0 ? (31 - bx) : bx;      // long segment first
        int q0 = qx * 64;

        short8 qf[4];
        {
            int qrow = q0 + w * 16 + (lane & 15);
            const u16* qp = Qb + (base + qrow) * DMODEL + h * 128 + ((lane >> 4) * 8);
#pragma unroll
            for (int ks = 0; ks < 4; ++ks) qf[ks] = *(const short8*)(qp + ks * 32);
        }

        f32x4 acc_o[8] = {};
        float m_run[4], l_run[4];
#pragma unroll
        for (int r = 0; r < 4; ++r) { m_run[r] = -1e30f; l_run[r] = 0.f; }

        int ntiles = qx + 1;
        for (int t = 0; t < ntiles; ++t) {
            size_t kv0 = (size_t)t * 64;
#pragma unroll
            for (int is = 0; is < 4; ++is)
                async16((const u16*)(Kbyte + ksrc[is] + kv0 * 256), (u16*)(kB + kd[is]));
#pragma unroll
            for (int is = 0; is < 4; ++is)
                async16((const u16*)(Vbyte + vsrc[is] + kv0 * 2), (u16*)(vB + kd[is]));
            __syncthreads();

            f32x4 sc[4];
            __builtin_amdgcn_s_setprio(1);
#pragma unroll
            for (int nb = 0; nb < 4; ++nb) {
                f32x4 a = {};
                int row = nb * 16 + (lane & 15);
                const char* kb_ = kB + row * 256;
                int x = (row & 7) << 4;
#pragma unroll
                for (int ks = 0; ks < 4; ++ks) {
                    short8 kf = *(const short8*)(kb_ + ((ks * 64 + (lane >> 4) * 16) ^ x));
                    a = __builtin_amdgcn_mfma_f32_16x16x32_bf16(qf[ks], kf, a, 0, 0, 0);
                }
                sc[nb] = a;
            }
            __builtin_amdgcn_s_setprio(0);

            if (t == qx) {     // diagonal tile: causal mask
                int kvb = t * 64;
                int qg = q0 + w * 16 + ((lane >> 4) << 2);
#pragma unroll
                for (int nb = 0; nb < 4; ++nb) {
                    int kc = kvb + nb * 16 + (lane & 15);
#pragma unroll
                    for (int r = 0; r < 4; ++r)
                        if (kc > qg + r) sc[nb][r] = -1e30f;
                }
            }
            float rmax[4];
#pragma unroll
            for (int r = 0; r < 4; ++r)
                rmax[r] = fmaxf(fmaxf(sc[0][r], sc[1][r]), fmaxf(sc[2][r], sc[3][r]));
#pragma unroll
            for (int off = 1; off < 16; off <<= 1)
#pragma unroll
                for (int r = 0; r < 4; ++r) rmax[r] = fmaxf(rmax[r], __shfl_xor(rmax[r], off));

            bool ok = (rmax[0] <= m_run[0]) & (rmax[1] <= m_run[1]) &
                      (rmax[2] <= m_run[2]) & (rmax[3] <= m_run[3]);
            if (!__all(ok)) {
                float fac[4];
#pragma unroll
                for (int r = 0; r < 4; ++r) {
                    float mnew = fmaxf(m_run[r], rmax[r]);
                    fac[r] = __expf(m_run[r] - mnew);
                    m_run[r] = mnew;
                    l_run[r] *= fac[r];
                }
#pragma unroll
                for (int db = 0; db < 8; ++db)
#pragma unroll
                    for (int r = 0; r < 4; ++r) acc_o[db][r] *= fac[r];
            }
#pragma unroll
            for (int nb = 0; nb < 4; ++nb)
#pragma unroll
                for (int r = 0; r < 4; ++r) {
                    float p = __expf(sc[nb][r] - m_run[r]);
                    sc[nb][r] = p; l_run[r] += p;
                }

            // P -> per-wave LDS, XOR-swizzled, truncation-convert (P in [0,1])
#pragma unroll
            for (int nb = 0; nb < 4; ++nb)
#pragma unroll
                for (int r = 0; r < 4; ++r) {
                    int row = ((lane >> 4) << 2) + r;
                    int cby = (nb * 32 + (lane & 15) * 2) ^ ((row & 7) << 4);
                    *(u16*)(pB + row * 128 + cby) = f2bf_trunc(sc[nb][r]);
                }
            __builtin_amdgcn_sched_barrier(0);
            __builtin_amdgcn_s_setprio(1);
#pragma unroll
            for (int ks = 0; ks < 2; ++ks) {
                int prow = lane & 15;
                short8 pf = *(const short8*)(pB + prow * 128 +
                                ((ks * 64 + (lane >> 4) * 16) ^ ((prow & 7) << 4)));
#pragma unroll
                for (int db = 0; db < 8; ++db) {
                    int row = db * 16 + (lane & 15);
                    const char* vb_ = vB + row * 128;
                    short8 vf = *(const short8*)(vb_ + ((ks * 64 + (lane >> 4) * 16) ^ ((row & 7) << 4)));
                    acc_o[db] = __builtin_amdgcn_mfma_f32_16x16x32_bf16(pf, vf, acc_o[db], 0, 0, 0);
                }
            }
            __builtin_amdgcn_s_setprio(0);
            __syncthreads();
        }

#pragma unroll
        for (int off = 1; off < 16; off <<= 1)
#pragma unroll
            for (int r = 0; r < 4; ++r) l_run[r] += __shfl_xor(l_run[r], off);

        int orow = q0 + w * 16 + ((lane >> 4) << 2);
#pragma unroll
        for (int db = 0; db < 8; ++db)
#pragma unroll
            for (int r = 0; r < 4; ++r) {
                float o = acc_o[db][r] / l_run[r];
                AO[(base + orow + r) * DMODEL + h * 128 + db * 16 + (lane & 15)] = f2bf(o);
            }
    }
}

// ---------------------------------------------------------------------------
extern "C" void kernel_launch(void* const* d_in, const int* in_sizes, int n_in,
                              void* d_out, int out_size, void* d_ws, size_t ws_size,
                              hipStream_t stream) {
    (void)in_sizes; (void)n_in; (void)out_size; (void)ws_size;
    const float* x      = (const float*)d_in[0];
    const float* W_dq   = (const float*)d_in[1];
    const float* W_uq   = (const float*)d_in[2];
    const float* q_ln_w = (const float*)d_in[3];
    const float* q_ln_b = (const float*)d_in[4];
    const float* W_dkv  = (const float*)d_in[5];
    const float* W_ukv  = (const float*)d_in[6];
    const float* kv_ln_w= (const float*)d_in[7];
    const float* kv_ln_b= (const float*)d_in[8];
    const float* W_o    = (const float*)d_in[9];

    float* out = (float*)d_out;
    float* ckv = out + (size_t)NROWS * DMODEL;   // output #2 region

    char* ws = (char*)d_ws;
    const size_t OFF_WDQT  = 0;
    const size_t OFF_WUQT  = 9437184;
    const size_t OFF_WDKVT = 18874368;
    const size_t OFF_WUKVT = 31850496;
    const size_t OFF_WO    = 50724864;
    const size_t OFF_XB    = 69599232;
    const size_t OFF_QB    = 94765056;
    const size_t OFF_KVB   = 119930880;
    const size_t OFF_KR    = 157679616;
    const size_t OFF_SLABA = 158203904;  // t0b bf16, later ao bf16
    const size_t OFF_SLABB = 183369728;  // cq bf16, later kvl bf16
    const size_t OFF_KP    = 0;          // over Wdq_t/Wuq_t/Wdkv_t (dead), 25.2MB
    const size_t OFF_VT    = OFF_XB;     // over xb (dead), 25.2MB

    u16* Wdq_t  = (u16*)(ws + OFF_WDQT);
    u16* Wuq_t  = (u16*)(ws + OFF_WUQT);
    u16* Wdkv_t = (u16*)(ws + OFF_WDKVT);
    u16* Wukv_t = (u16*)(ws + OFF_WUKVT);
    u16* Wo_b   = (u16*)(ws + OFF_WO);
    u16* xb     = (u16*)(ws + OFF_XB);
    u16* qb     = (u16*)(ws + OFF_QB);
    u16* KVb    = (u16*)(ws + OFF_KVB);
    u16* kr     = (u16*)(ws + OFF_KR);
    u16* t0b    = (u16*)(ws + OFF_SLABA);
    u16* ao     = (u16*)(ws + OFF_SLABA);
    u16* cq     = (u16*)(ws + OFF_SLABB);
    u16* kvl    = (u16*)(ws + OFF_SLABB);
    u16* Kp     = (u16*)(ws + OFF_KP);
    u16* Vt     = (u16*)(ws + OFF_VT);

    const float SCALE = 0.08838834764831845f;    // 1/sqrt(128), folded into W_uq

    // weight prep
    transpose_bf16<<<dim3(QPROJ / 32, DMODEL / 32), 256, 0, stream>>>(W_dq,  Wdq_t,  DMODEL, QPROJ, 1.0f);
    transpose_bf16<<<dim3(DMODEL / 32, QPROJ / 32), 256, 0, stream>>>(W_uq,  Wuq_t,  QPROJ, DMODEL, SCALE);
    transpose_bf16<<<dim3(CKV_W / 32, DMODEL / 32), 256, 0, stream>>>(W_dkv, Wdkv_t, DMODEL, CKV_W, 1.0f);
    transpose_bf16<<<dim3(UKV_N / 32, KVPROJ / 32), 256, 0, stream>>>(W_ukv, Wukv_t, KVPROJ, UKV_N, 1.0f);
    conv_bf16<<<9216, 256, 0, stream>>>(W_o, Wo_b, DMODEL * DMODEL);
    conv_bf16<<<12288, 256, 0, stream>>>(x, xb, NROWS * DMODEL);

    // q path  (flat XCD-chunked grids: nwg = nx*ny, all divisible by 8)
    gemm_nt<true><<<(QPROJ / 128) * (NROWS / 128), 256, 0, stream>>>(xb, Wdq_t, t0b, NROWS, QPROJ, DMODEL, QPROJ / 128);
    ln_bf16_kernel<<<NROWS, 256, 0, stream>>>(t0b, q_ln_w, q_ln_b, cq, QPROJ);
    gemm_nt<true><<<(DMODEL / 128) * (NROWS / 128), 256, 0, stream>>>(cq, Wuq_t, qb, NROWS, DMODEL, QPROJ, DMODEL / 128);
    rope_q_kernel<<<12288, 256, 0, stream>>>(qb);

    // kv path
    gemm_nt<false><<<17 * (NROWS / 128), 256, 0, stream>>>(xb, Wdkv_t, ckv, NROWS, CKV_W, DMODEL, 17);
    ln_kernel<<<NROWS, 256, 0, stream>>>(ckv, CKV_W, kv_ln_w, kv_ln_b, kvl, KVPROJ);
    rope_k_kernel<<<512, 256, 0, stream>>>(ckv, kr);
    gemm_nt<true><<<(UKV_N / 128) * (NROWS / 128), 256, 0, stream>>>(kvl, Wukv_t, KVb, NROWS, UKV_N, KVPROJ, UKV_N / 128);

    // pack K/V for attention (Wdq_t/Wuq_t/Wdkv_t and xb are dead now)
    pack_k<<<dim3(S_LEN / 64, 2 * NHEADS), 256, 0, stream>>>(KVb, kr, Kp);
    pack_v<<<dim3(S_LEN / 64, 2 * NHEADS), 256, 0, stream>>>(KVb, Vt);

    // attention (768 uniform paired blocks, XCD head-clustered)
    attn_kernel<<<768, 256, 0, stream>>>(qb, Kp, Vt, ao);

    // output projection
    gemm_nt<false><<<(DMODEL / 128) * (NROWS / 128), 256, 0, stream>>>(ao, Wo_b, out, NROWS, DMODEL, DMODEL, DMODEL / 128);
}

// Round 15
// 612.620 us; speedup vs baseline: 1.0636x; 1.0344x over previous
//
#include <hip/hip_runtime.h>

typedef unsigned short u16;
typedef __attribute__((ext_vector_type(8))) short short8;
typedef __attribute__((ext_vector_type(4))) float f32x4;

#define NROWS   4096     // B*S
#define S_LEN   2048
#define NHEADS  24
#define DMODEL  3072
#define QPROJ   1536
#define KVPROJ  2048
#define CKV_W   2112     // KVPROJ + 64 rope
#define UKV_N   4608     // DMODEL + 24*64

__device__ __forceinline__ float bf2f(u16 v) {
    unsigned u = ((unsigned)v) << 16; float f; __builtin_memcpy(&f, &u, 4); return f;
}
__device__ __forceinline__ u16 f2bf(float f) {
    unsigned u; __builtin_memcpy(&u, &f, 4);
    u = (u + 0x7FFFu + ((u >> 16) & 1u)) >> 16; return (u16)u;
}
__device__ __forceinline__ u16 f2bf_trunc(float f) {
    unsigned u; __builtin_memcpy(&u, &f, 4);
    return (u16)(u >> 16);
}
__device__ __forceinline__ void async16(const u16* g, u16* l) {
    __builtin_amdgcn_global_load_lds((const __attribute__((address_space(1))) unsigned int*)g,
                                     (__attribute__((address_space(3))) unsigned int*)l,
                                     16, 0, 0);
}

// ---------------- elementwise convert fp32 -> bf16 (vectorized) -------------
__global__ void conv_bf16(const float* __restrict__ X, u16* __restrict__ Y, int n) {
    int i = (blockIdx.x * 256 + threadIdx.x) * 4;
    if (i >= n) return;
    float4 v = *(const float4*)(X + i);
    Y[i+0] = f2bf(v.x); Y[i+1] = f2bf(v.y); Y[i+2] = f2bf(v.z); Y[i+3] = f2bf(v.w);
}

// ---------------- transpose + convert + scale: W (K x N) -> WT (N x K) bf16 -
__global__ void transpose_bf16(const float* __restrict__ W, u16* __restrict__ WT,
                               int K, int N, float scale) {
    __shared__ float t[32][33];
    int nb = blockIdx.x * 32, kb = blockIdx.y * 32;
    int c = threadIdx.x & 31, rq = threadIdx.x >> 5;
#pragma unroll
    for (int i = 0; i < 4; ++i) {
        int r = rq * 4 + i;
        t[r][c] = W[(size_t)(kb + r) * N + nb + c];
    }
    __syncthreads();
#pragma unroll
    for (int i = 0; i < 4; ++i) {
        int r = rq * 4 + i;
        WT[(size_t)(nb + r) * K + kb + c] = f2bf(t[c][r] * scale);
    }
}

// ---------------- LayerNorm (fp32 in, bf16 out), float4-vectorized ----------
__global__ __launch_bounds__(256) void ln_kernel(const float* __restrict__ X, int ldx,
                                                 const float* __restrict__ g,
                                                 const float* __restrict__ b,
                                                 u16* __restrict__ Y, int W) {
    int row = blockIdx.x;
    const float4* x4 = (const float4*)(X + (size_t)row * ldx);
    int W4 = W >> 2;
    float s = 0.f, s2 = 0.f;
    for (int i = threadIdx.x; i < W4; i += 256) {
        float4 v = x4[i];
        s += v.x + v.y + v.z + v.w;
        s2 += v.x * v.x + v.y * v.y + v.z * v.z + v.w * v.w;
    }
#pragma unroll
    for (int off = 32; off >= 1; off >>= 1) { s += __shfl_xor(s, off); s2 += __shfl_xor(s2, off); }
    __shared__ float red[8];
    int w = threadIdx.x >> 6;
    if ((threadIdx.x & 63) == 0) { red[w] = s; red[4 + w] = s2; }
    __syncthreads();
    s  = red[0] + red[1] + red[2] + red[3];
    s2 = red[4] + red[5] + red[6] + red[7];
    float mean = s / W;
    float var  = s2 / W - mean * mean;
    float rstd = rsqrtf(var + 1e-5f);
    const float4* g4 = (const float4*)g;
    const float4* b4 = (const float4*)b;
    u16* y = Y + (size_t)row * W;
    for (int i = threadIdx.x; i < W4; i += 256) {
        float4 v = x4[i], gg = g4[i], bb = b4[i];
        u16 o[4];
        o[0] = f2bf((v.x - mean) * rstd * gg.x + bb.x);
        o[1] = f2bf((v.y - mean) * rstd * gg.y + bb.y);
        o[2] = f2bf((v.z - mean) * rstd * gg.z + bb.z);
        o[3] = f2bf((v.w - mean) * rstd * gg.w + bb.w);
        *(ulong1*)&y[i * 4] = *(ulong1*)o;
    }
}

// ---------------- LayerNorm (bf16 in, bf16 out), 4-elem vectorized ----------
__global__ __launch_bounds__(256) void ln_bf16_kernel(const u16* __restrict__ X,
                                                      const float* __restrict__ g,
                                                      const float* __restrict__ b,
                                                      u16* __restrict__ Y, int W) {
    int row = blockIdx.x;
    const u16* x = X + (size_t)row * W;
    int W4 = W >> 2;
    float s = 0.f, s2 = 0.f;
    for (int i = threadIdx.x; i < W4; i += 256) {
        ushort4 v = *(const ushort4*)(x + i * 4);
        float a0 = bf2f(v.x), a1 = bf2f(v.y), a2 = bf2f(v.z), a3 = bf2f(v.w);
        s += a0 + a1 + a2 + a3;
        s2 += a0 * a0 + a1 * a1 + a2 * a2 + a3 * a3;
    }
#pragma unroll
    for (int off = 32; off >= 1; off >>= 1) { s += __shfl_xor(s, off); s2 += __shfl_xor(s2, off); }
    __shared__ float red[8];
    int w = threadIdx.x >> 6;
    if ((threadIdx.x & 63) == 0) { red[w] = s; red[4 + w] = s2; }
    __syncthreads();
    s  = red[0] + red[1] + red[2] + red[3];
    s2 = red[4] + red[5] + red[6] + red[7];
    float mean = s / W;
    float var  = s2 / W - mean * mean;
    float rstd = rsqrtf(var + 1e-5f);
    const float4* g4 = (const float4*)g;
    const float4* b4 = (const float4*)b;
    u16* y = Y + (size_t)row * W;
    for (int i = threadIdx.x; i < W4; i += 256) {
        ushort4 v = *(const ushort4*)(x + i * 4);
        float4 gg = g4[i], bb = b4[i];
        u16 o[4];
        o[0] = f2bf((bf2f(v.x) - mean) * rstd * gg.x + bb.x);
        o[1] = f2bf((bf2f(v.y) - mean) * rstd * gg.y + bb.y);
        o[2] = f2bf((bf2f(v.z) - mean) * rstd * gg.z + bb.z);
        o[3] = f2bf((bf2f(v.w) - mean) * rstd * gg.w + bb.w);
        *(ulong1*)&y[i * 4] = *(ulong1*)o;
    }
}

// ---------------- RoPE on K_rope (from fp32 ckv -> bf16 kr) -----------------
__global__ void rope_k_kernel(const float* __restrict__ ckv, u16* __restrict__ kr) {
    int idx = blockIdx.x * 256 + threadIdx.x;       // NROWS*32
    int j = idx & 31; int row = idx >> 5;
    int s = row & (S_LEN - 1);
    float freq = __expf(-(float)j * (9.210340371976184f / 64.f));
    float ang = (float)s * freq;
    float c = cosf(ang), si = sinf(ang);
    const float* src = ckv + (size_t)row * CKV_W + KVPROJ;
    float x1 = src[j], x2 = src[j + 32];
    kr[(size_t)row * 64 + j]      = f2bf(x1 * c - x2 * si);
    kr[(size_t)row * 64 + j + 32] = f2bf(x2 * c + x1 * si);
}

// ---------------- GEMM 128x128, BK=32, dbuf + swizzle, XCD-chunked grid -----
// MODE: 0 = fp32 out, 1 = bf16 out, 2 = bf16 + fused RoPE-Q (N=3072 layout),
//       3 = fused MLA pack (c<64 -> Kn[bh][s][64], c>=64 -> Vt[bh][c-64][s])
template<int MODE>
__global__ __launch_bounds__(256) void gemm_nt(const u16* __restrict__ A,
                                               const u16* __restrict__ B,
                                               void* __restrict__ Cv,
                                               u16* __restrict__ Kn,
                                               u16* __restrict__ Vt,
                                               int M, int N, int K, int nx) {
    __shared__ u16 a_lds[2][128][32];
    __shared__ u16 b_lds[2][128][32];
    int nwg = (int)gridDim.x;
    int bid = (int)blockIdx.x;
    int wg = (bid & 7) * (nwg >> 3) + (bid >> 3);
    int by = wg / nx, bx = wg - by * nx;
    int m0 = by * 128, n0 = bx * 128;
    int tid = threadIdx.x, lane = tid & 63, w = tid >> 6;
    int wm = w >> 1, wn = w & 1;
    int srow = lane >> 2;
    int kx = (lane >> 4) & 2;
    int scol = ((lane & 3) ^ kx) * 8;
    int r0 = w * 32 + srow, r1 = w * 32 + 16 + srow;
    const u16* A0 = A + (size_t)(m0 + r0) * K + scol;
    const u16* A1 = A + (size_t)(m0 + r1) * K + scol;
    int bn0 = n0 + r0; if (bn0 >= N) bn0 = N - 1;
    int bn1 = n0 + r1; if (bn1 >= N) bn1 = N - 1;
    const u16* B0 = B + (size_t)bn0 * K + scol;
    const u16* B1 = B + (size_t)bn1 * K + scol;
    char* aB = (char*)&a_lds[0][0][0];
    char* bB = (char*)&b_lds[0][0][0];
    int d0 = w * 2048, d1 = w * 2048 + 1024;
    int cb = ((lane >> 4) * 16) ^ ((lane & 8) << 2);

    f32x4 acc[4][4] = {};
    async16(A0, (u16*)(aB + d0)); async16(A1, (u16*)(aB + d1));
    async16(B0, (u16*)(bB + d0)); async16(B1, (u16*)(bB + d1));
    __syncthreads();
    int buf = 0;
    for (int kb = 0; kb < K; kb += 32) {
        if (kb + 32 < K) {
            int ob = (buf ^ 1) * 8192;
            async16(A0 + kb + 32, (u16*)(aB + ob + d0));
            async16(A1 + kb + 32, (u16*)(aB + ob + d1));
            async16(B0 + kb + 32, (u16*)(bB + ob + d0));
            async16(B1 + kb + 32, (u16*)(bB + ob + d1));
        }
        const char* ab = aB + buf * 8192;
        const char* bb = bB + buf * 8192;
        short8 af[4], bf[4];
#pragma unroll
        for (int i = 0; i < 4; ++i) {
            af[i] = *(const short8*)(ab + (wm * 64 + i * 16 + (lane & 15)) * 64 + cb);
            bf[i] = *(const short8*)(bb + (wn * 64 + i * 16 + (lane & 15)) * 64 + cb);
        }
#pragma unroll
        for (int i = 0; i < 4; ++i)
#pragma unroll
            for (int j = 0; j < 4; ++j)
                acc[i][j] = __builtin_amdgcn_mfma_f32_16x16x32_bf16(af[i], bf[j], acc[i][j], 0, 0, 0);
        __syncthreads();
        buf ^= 1;
    }

    if (MODE == 2 && wn == 1) {
        // fused RoPE-Q: cols 64..127 of head n0/128; pair (c, c+32) = (j, j+2)
#pragma unroll
        for (int i = 0; i < 4; ++i) {
            int rowg = m0 + wm * 64 + i * 16 + ((lane >> 4) << 2);
#pragma unroll
            for (int j = 0; j < 2; ++j) {
                int jf = j * 16 + (lane & 15);   // 0..31
                float freq = __expf(-(float)jf * (9.210340371976184f / 64.f));
#pragma unroll
                for (int r = 0; r < 4; ++r) {
                    int s = (rowg + r) & (S_LEN - 1);
                    float ang = (float)s * freq;
                    float cs, sn;
                    __sincosf(ang, &sn, &cs);
                    float x1 = acc[i][j][r], x2 = acc[i][j + 2][r];
                    acc[i][j][r]     = x1 * cs - x2 * sn;
                    acc[i][j + 2][r] = x2 * cs + x1 * sn;
                }
            }
        }
    }

    if (MODE == 3) {
        // fused MLA pack: head = col/192; c<64 -> Kn, c>=64 -> Vt (transposed)
#pragma unroll
        for (int i = 0; i < 4; ++i) {
            int rowg = m0 + wm * 64 + i * 16 + ((lane >> 4) << 2);
            int bb = rowg >> 11;
            int s0 = rowg & (S_LEN - 1);
#pragma unroll
            for (int j = 0; j < 4; ++j) {
                int colbase = n0 + wn * 64 + j * 16;   // fragment never straddles 192k
                int h = colbase / 192;
                int c = colbase - h * 192 + (lane & 15);
                int bh = bb * NHEADS + h;
                if (c < 64) {
#pragma unroll
                    for (int r = 0; r < 4; ++r)
                        Kn[((size_t)bh * S_LEN + s0 + r) * 64 + c] = f2bf(acc[i][j][r]);
                } else {
                    size_t vb = ((size_t)bh * 128 + (c - 64)) * S_LEN + s0;
                    u16 o[4];
#pragma unroll
                    for (int r = 0; r < 4; ++r) o[r] = f2bf(acc[i][j][r]);
                    *(ushort4*)&Vt[vb] = *(ushort4*)o;
                }
            }
        }
        return;
    }

#pragma unroll
    for (int i = 0; i < 4; ++i) {
        int row = m0 + wm * 64 + i * 16 + ((lane >> 4) << 2);
#pragma unroll
        for (int j = 0; j < 4; ++j) {
            int col = n0 + wn * 64 + j * 16 + (lane & 15);
            if (col < N) {
#pragma unroll
                for (int r = 0; r < 4; ++r) {
                    if (MODE != 0) ((u16*)Cv)[(size_t)(row + r) * N + col] = f2bf(acc[i][j][r]);
                    else           ((float*)Cv)[(size_t)(row + r) * N + col] = acc[i][j][r];
                }
            }
        }
    }
}

// ---------------- Flash attention: paired causal blocks, XCD-clustered ------
// K tile staged from TWO sources (Kn nope rows + shared kr rope rows, both
// 128 B/row); V from Vt. Same LDS layout/swizzle/read path as R14.
__global__ __launch_bounds__(256) void attn_kernel(const u16* __restrict__ Qb,
                                                   const u16* __restrict__ Kn,
                                                   const u16* __restrict__ kr_,
                                                   const u16* __restrict__ Vt,
                                                   u16* __restrict__ AO) {
    __shared__ u16 k_lds[64][128];     // 16 KB
    __shared__ u16 v_lds[128][64];     // 16 KB
    __shared__ u16 p_lds[4][16][64];   // 8 KB (XOR-swizzled) -> total 40960 B
    int bid = blockIdx.x;
    int jj = bid >> 3;
    int bh = (bid & 7) * 6 + (jj >> 4);          // all 16 blocks of a head on one XCD
    int bx = jj & 15;
    int bb = bh / NHEADS, h = bh % NHEADS;
    int tid = threadIdx.x, lane = tid & 63, w = tid >> 6;
    size_t base = (size_t)bb * S_LEN;
    size_t bhS = (size_t)bh * S_LEN;

    const char* Vbyte = (const char*)Vt;
    char* kB = (char*)&k_lds[0][0];
    char* vB = (char*)&v_lds[0][0];
    char* pB = (char*)&p_lds[0][0][0] + w * 2048;   // per-wave 16x128B
    const char* psrc[4];
    size_t vsrc[4];
    int kd[4];
#pragma unroll
    for (int is = 0; is < 4; ++is) {
        int j = is * 256 + tid;
        int r = j >> 4;                      // kv row within tile
        int p = j & 15;                      // physical chunk
        int lq = p ^ (r & 7);                // logical chunk
        if (lq < 8) psrc[is] = (const char*)Kn  + (bhS  + r) * 128 + lq * 16;
        else        psrc[is] = (const char*)kr_ + (base + r) * 128 + (lq - 8) * 16;
        int d = j >> 3;
        int kbs = (((j & 7) ^ (d & 7)) * 16);
        vsrc[is] = ((size_t)bh * 128 + d) * (S_LEN * 2) + kbs;
        kd[is] = (is * 256 + w * 64) * 16;
    }

    for (int seg = 0; seg < 2; ++seg) {
        int qx = seg == 0 ? (31 - bx) : bx;      // long segment first
        int q0 = qx * 64;

        short8 qf[4];
        {
            int qrow = q0 + w * 16 + (lane & 15);
            const u16* qp = Qb + (base + qrow) * DMODEL + h * 128 + ((lane >> 4) * 8);
#pragma unroll
            for (int ks = 0; ks < 4; ++ks) qf[ks] = *(const short8*)(qp + ks * 32);
        }

        f32x4 acc_o[8] = {};
        float m_run[4], l_run[4];
#pragma unroll
        for (int r = 0; r < 4; ++r) { m_run[r] = -1e30f; l_run[r] = 0.f; }

        int ntiles = qx + 1;
        for (int t = 0; t < ntiles; ++t) {
            size_t kv0 = (size_t)t * 64;
#pragma unroll
            for (int is = 0; is < 4; ++is)
                async16((const u16*)(psrc[is] + kv0 * 128), (u16*)(kB + kd[is]));
#pragma unroll
            for (int is = 0; is < 4; ++is)
                async16((const u16*)(Vbyte + vsrc[is] + kv0 * 2), (u16*)(vB + kd[is]));
            __syncthreads();

            f32x4 sc[4];
            __builtin_amdgcn_s_setprio(1);
#pragma unroll
            for (int nb = 0; nb < 4; ++nb) {
                f32x4 a = {};
                int row = nb * 16 + (lane & 15);
                const char* kb_ = kB + row * 256;
                int x = (row & 7) << 4;
#pragma unroll
                for (int ks = 0; ks < 4; ++ks) {
                    short8 kf = *(const short8*)(kb_ + ((ks * 64 + (lane >> 4) * 16) ^ x));
                    a = __builtin_amdgcn_mfma_f32_16x16x32_bf16(qf[ks], kf, a, 0, 0, 0);
                }
                sc[nb] = a;
            }
            __builtin_amdgcn_s_setprio(0);

            if (t == qx) {     // diagonal tile: causal mask
                int kvb = t * 64;
                int qg = q0 + w * 16 + ((lane >> 4) << 2);
#pragma unroll
                for (int nb = 0; nb < 4; ++nb) {
                    int kc = kvb + nb * 16 + (lane & 15);
#pragma unroll
                    for (int r = 0; r < 4; ++r)
                        if (kc > qg + r) sc[nb][r] = -1e30f;
                }
            }
            float rmax[4];
#pragma unroll
            for (int r = 0; r < 4; ++r)
                rmax[r] = fmaxf(fmaxf(sc[0][r], sc[1][r]), fmaxf(sc[2][r], sc[3][r]));
#pragma unroll
            for (int off = 1; off < 16; off <<= 1)
#pragma unroll
                for (int r = 0; r < 4; ++r) rmax[r] = fmaxf(rmax[r], __shfl_xor(rmax[r], off));

            bool ok = (rmax[0] <= m_run[0]) & (rmax[1] <= m_run[1]) &
                      (rmax[2] <= m_run[2]) & (rmax[3] <= m_run[3]);
            if (!__all(ok)) {
                float fac[4];
#pragma unroll
                for (int r = 0; r < 4; ++r) {
                    float mnew = fmaxf(m_run[r], rmax[r]);
                    fac[r] = __expf(m_run[r] - mnew);
                    m_run[r] = mnew;
                    l_run[r] *= fac[r];
                }
#pragma unroll
                for (int db = 0; db < 8; ++db)
#pragma unroll
                    for (int r = 0; r < 4; ++r) acc_o[db][r] *= fac[r];
            }
#pragma unroll
            for (int nb = 0; nb < 4; ++nb)
#pragma unroll
                for (int r = 0; r < 4; ++r) {
                    float p = __expf(sc[nb][r] - m_run[r]);
                    sc[nb][r] = p; l_run[r] += p;
                }

            // P -> per-wave LDS, XOR-swizzled, truncation-convert (P in [0,1])
#pragma unroll
            for (int nb = 0; nb < 4; ++nb)
#pragma unroll
                for (int r = 0; r < 4; ++r) {
                    int row = ((lane >> 4) << 2) + r;
                    int cby = (nb * 32 + (lane & 15) * 2) ^ ((row & 7) << 4);
                    *(u16*)(pB + row * 128 + cby) = f2bf_trunc(sc[nb][r]);
                }
            __builtin_amdgcn_sched_barrier(0);
            __builtin_amdgcn_s_setprio(1);
#pragma unroll
            for (int ks = 0; ks < 2; ++ks) {
                int prow = lane & 15;
                short8 pf = *(const short8*)(pB + prow * 128 +
                                ((ks * 64 + (lane >> 4) * 16) ^ ((prow & 7) << 4)));
#pragma unroll
                for (int db = 0; db < 8; ++db) {
                    int row = db * 16 + (lane & 15);
                    const char* vb_ = vB + row * 128;
                    short8 vf = *(const short8*)(vb_ + ((ks * 64 + (lane >> 4) * 16) ^ ((row & 7) << 4)));
                    acc_o[db] = __builtin_amdgcn_mfma_f32_16x16x32_bf16(pf, vf, acc_o[db], 0, 0, 0);
                }
            }
            __builtin_amdgcn_s_setprio(0);
            __syncthreads();
        }

#pragma unroll
        for (int off = 1; off < 16; off <<= 1)
#pragma unroll
            for (int r = 0; r < 4; ++r) l_run[r] += __shfl_xor(l_run[r], off);

        int orow = q0 + w * 16 + ((lane >> 4) << 2);
#pragma unroll
        for (int db = 0; db < 8; ++db)
#pragma unroll
            for (int r = 0; r < 4; ++r) {
                float o = acc_o[db][r] / l_run[r];
                AO[(base + orow + r) * DMODEL + h * 128 + db * 16 + (lane & 15)] = f2bf(o);
            }
    }
}

// ---------------------------------------------------------------------------
extern "C" void kernel_launch(void* const* d_in, const int* in_sizes, int n_in,
                              void* d_out, int out_size, void* d_ws, size_t ws_size,
                              hipStream_t stream) {
    (void)in_sizes; (void)n_in; (void)out_size; (void)ws_size;
    const float* x      = (const float*)d_in[0];
    const float* W_dq   = (const float*)d_in[1];
    const float* W_uq   = (const float*)d_in[2];
    const float* q_ln_w = (const float*)d_in[3];
    const float* q_ln_b = (const float*)d_in[4];
    const float* W_dkv  = (const float*)d_in[5];
    const float* W_ukv  = (const float*)d_in[6];
    const float* kv_ln_w= (const float*)d_in[7];
    const float* kv_ln_b= (const float*)d_in[8];
    const float* W_o    = (const float*)d_in[9];

    float* out = (float*)d_out;
    float* ckv = out + (size_t)NROWS * DMODEL;   // output #2 region

    char* ws = (char*)d_ws;
    const size_t OFF_WDQT  = 0;
    const size_t OFF_WUQT  = 9437184;
    const size_t OFF_WDKVT = 18874368;
    const size_t OFF_WUKVT = 31850496;
    const size_t OFF_WO    = 50724864;
    const size_t OFF_XB    = 69599232;
    const size_t OFF_QB    = 94765056;
    const size_t OFF_KN    = 119930880;  // 12.6 MB (2*24*2048*64 bf16)
    const size_t OFF_KR    = 157679616;
    const size_t OFF_SLABA = 158203904;  // t0b bf16, later ao bf16
    const size_t OFF_SLABB = 183369728;  // cq bf16, later kvl bf16
    const size_t OFF_VT    = OFF_XB;     // over xb (dead after W_dkv gemm), 25.2MB

    u16* Wdq_t  = (u16*)(ws + OFF_WDQT);
    u16* Wuq_t  = (u16*)(ws + OFF_WUQT);
    u16* Wdkv_t = (u16*)(ws + OFF_WDKVT);
    u16* Wukv_t = (u16*)(ws + OFF_WUKVT);
    u16* Wo_b   = (u16*)(ws + OFF_WO);
    u16* xb     = (u16*)(ws + OFF_XB);
    u16* qb     = (u16*)(ws + OFF_QB);
    u16* Kn     = (u16*)(ws + OFF_KN);
    u16* kr     = (u16*)(ws + OFF_KR);
    u16* t0b    = (u16*)(ws + OFF_SLABA);
    u16* ao     = (u16*)(ws + OFF_SLABA);
    u16* cq     = (u16*)(ws + OFF_SLABB);
    u16* kvl    = (u16*)(ws + OFF_SLABB);
    u16* Vt     = (u16*)(ws + OFF_VT);

    const float SCALE = 0.08838834764831845f;    // 1/sqrt(128), folded into W_uq

    // weight prep
    transpose_bf16<<<dim3(QPROJ / 32, DMODEL / 32), 256, 0, stream>>>(W_dq,  Wdq_t,  DMODEL, QPROJ, 1.0f);
    transpose_bf16<<<dim3(DMODEL / 32, QPROJ / 32), 256, 0, stream>>>(W_uq,  Wuq_t,  QPROJ, DMODEL, SCALE);
    transpose_bf16<<<dim3(CKV_W / 32, DMODEL / 32), 256, 0, stream>>>(W_dkv, Wdkv_t, DMODEL, CKV_W, 1.0f);
    transpose_bf16<<<dim3(UKV_N / 32, KVPROJ / 32), 256, 0, stream>>>(W_ukv, Wukv_t, KVPROJ, UKV_N, 1.0f);
    conv_bf16<<<9216, 256, 0, stream>>>(W_o, Wo_b, DMODEL * DMODEL);
    conv_bf16<<<12288, 256, 0, stream>>>(x, xb, NROWS * DMODEL);

    // q path  (flat XCD-chunked grids: nwg = nx*ny, all divisible by 8)
    gemm_nt<1><<<(QPROJ / 128) * (NROWS / 128), 256, 0, stream>>>(xb, Wdq_t, t0b, nullptr, nullptr, NROWS, QPROJ, DMODEL, QPROJ / 128);
    ln_bf16_kernel<<<NROWS, 256, 0, stream>>>(t0b, q_ln_w, q_ln_b, cq, QPROJ);
    gemm_nt<2><<<(DMODEL / 128) * (NROWS / 128), 256, 0, stream>>>(cq, Wuq_t, qb, nullptr, nullptr, NROWS, DMODEL, QPROJ, DMODEL / 128);

    // kv path
    gemm_nt<0><<<17 * (NROWS / 128), 256, 0, stream>>>(xb, Wdkv_t, ckv, nullptr, nullptr, NROWS, CKV_W, DMODEL, 17);
    ln_kernel<<<NROWS, 256, 0, stream>>>(ckv, CKV_W, kv_ln_w, kv_ln_b, kvl, KVPROJ);
    rope_k_kernel<<<512, 256, 0, stream>>>(ckv, kr);
    gemm_nt<3><<<(UKV_N / 128) * (NROWS / 128), 256, 0, stream>>>(kvl, Wukv_t, nullptr, Kn, Vt, NROWS, UKV_N, KVPROJ, UKV_N / 128);

    // attention (768 uniform paired blocks, XCD head-clustered)
    attn_kernel<<<768, 256, 0, stream>>>(qb, Kn, kr, Vt, ao);

    // output projection
    gemm_nt<0><<<(DMODEL / 128) * (NROWS / 128), 256, 0, stream>>>(ao, Wo_b, out, nullptr, nullptr, NROWS, DMODEL, DMODEL, DMODEL / 128);
}